// Round 1
// baseline (332.561 us; speedup 1.0000x reference)
//
#include <hip/hip_runtime.h>
#include <hip/hip_bf16.h>
#include <stdint.h>

#define NSPEC 16
#define IN_DIM 256
#define HID 512
#define ODIM 1024
#define NA 512
#define NB 32
#define NROWS (NA*NB)
#define NSLOTS 144

typedef __bf16 bf16x8 __attribute__((ext_vector_type(8)));
typedef float f32x4 __attribute__((ext_vector_type(4)));

__device__ __forceinline__ uint32_t f2bf1(float f){
  uint32_t u = __builtin_bit_cast(uint32_t, f);
  u += 0x7FFFu + ((u >> 16) & 1u);   // RNE
  return u >> 16;
}
__device__ __forceinline__ uint32_t pack2(float a, float b){
  return f2bf1(a) | (f2bf1(b) << 16);
}
__device__ __forceinline__ uint4 load8_pack(const float* __restrict__ src){
  float4 f0 = *reinterpret_cast<const float4*>(src);
  float4 f1 = *reinterpret_cast<const float4*>(src + 4);
  uint4 v;
  v.x = pack2(f0.x, f0.y); v.y = pack2(f0.z, f0.w);
  v.z = pack2(f1.x, f1.y); v.w = pack2(f1.z, f1.w);
  return v;
}
__device__ __forceinline__ float sigm(float x){ return 1.0f / (1.0f + __expf(-x)); }

// ---------------- prep: group a-indices by species into slots of <=4 ----------------
__global__ void k_prep(const int* __restrict__ sp, int* __restrict__ order,
                       int* __restrict__ slot_s, int* __restrict__ slot_st,
                       int* __restrict__ slot_na){
  __shared__ int cnt[NSPEC], off[NSPEC], cur[NSPEC];
  int t = threadIdx.x;
  if (t < NSPEC) cnt[t] = 0;
  __syncthreads();
  int s = sp[t];
  atomicAdd(&cnt[s], 1);
  __syncthreads();
  if (t == 0){
    int o = 0;
    for (int i = 0; i < NSPEC; i++){ off[i] = o; cur[i] = o; o += cnt[i]; }
  }
  __syncthreads();
  int pos = atomicAdd(&cur[s], 1);
  order[pos] = t;
  __syncthreads();
  if (t == 0){
    int k = 0;
    for (int i = 0; i < NSPEC; i++){
      int c = cnt[i], st = off[i];
      for (int j = 0; j < c; j += 4){
        slot_s[k] = i; slot_st[k] = st + j;
        slot_na[k] = (c - j < 4) ? (c - j) : 4; k++;
      }
    }
    for (; k < NSLOTS; k++){ slot_s[k] = 0; slot_st[k] = 0; slot_na[k] = 0; }
  }
}

// ---------------- stage 1: x_proj = relu(x @ w_in[s]^T + b_in[s]) -> bf16 ----------------
// grid (4 ntiles of 128, NSLOTS), 256 threads. BM=128 (4 a of same species), K=256.
__global__ __launch_bounds__(256) void k_xproj(
    const float* __restrict__ x, const float* __restrict__ w_in,
    const float* __restrict__ b_in,
    const int* __restrict__ order, const int* __restrict__ slot_s,
    const int* __restrict__ slot_st, const int* __restrict__ slot_na,
    ushort* __restrict__ xproj)
{
  int slot = blockIdx.y;
  int na = slot_na[slot];
  if (na == 0) return;
  int spec = slot_s[slot];
  int start = slot_st[slot];
  int n0 = blockIdx.x * 128;
  int tid = threadIdx.x, lane = tid & 63, wid = tid >> 6;
  int mh = wid >> 1, nh = wid & 1;

  __shared__ uint4 ldsA[128 * 8];
  __shared__ uint4 ldsB[128 * 8];

  int arow[4];
#pragma unroll
  for (int i = 0; i < 4; i++) arow[i] = (i < na) ? order[start + i] : 0;

  f32x4 acc[4][4];
#pragma unroll
  for (int i = 0; i < 4; i++)
#pragma unroll
    for (int j = 0; j < 4; j++) acc[i][j] = (f32x4){0.f, 0.f, 0.f, 0.f};

  for (int ch = 0; ch < 4; ++ch){
    int k0 = ch * 64;
#pragma unroll
    for (int i = 0; i < 4; i++){            // A: x rows (masked)
      int u = tid + i * 256;
      int r = u >> 3, uu = u & 7;
      int ai = r >> 5;
      uint4 v = {0u, 0u, 0u, 0u};
      if (ai < na){
        const float* src = x + ((size_t)(arow[ai] * NB + (r & 31))) * IN_DIM + k0 + uu * 8;
        v = load8_pack(src);
      }
      ldsA[r * 8 + (uu ^ (r & 7))] = v;
    }
#pragma unroll
    for (int i = 0; i < 4; i++){            // B: w_in[s] rows
      int u = tid + i * 256;
      int r = u >> 3, uu = u & 7;
      const float* src = w_in + ((size_t)(spec * HID + n0 + r)) * IN_DIM + k0 + uu * 8;
      ldsB[r * 8 + (uu ^ (r & 7))] = load8_pack(src);
    }
    __syncthreads();
#pragma unroll
    for (int kk = 0; kk < 2; ++kk){
      int lr = lane & 15, lk = (lane >> 4) + kk * 4;
      bf16x8 af[4], bfr[4];
#pragma unroll
      for (int mt = 0; mt < 4; mt++){
        int r = mh * 64 + mt * 16 + lr;
        af[mt] = __builtin_bit_cast(bf16x8, ldsA[r * 8 + (lk ^ (r & 7))]);
      }
#pragma unroll
      for (int nt = 0; nt < 4; nt++){
        int r = nh * 64 + nt * 16 + lr;
        bfr[nt] = __builtin_bit_cast(bf16x8, ldsB[r * 8 + (lk ^ (r & 7))]);
      }
#pragma unroll
      for (int mt = 0; mt < 4; mt++)
#pragma unroll
        for (int nt = 0; nt < 4; nt++)
          acc[mt][nt] = __builtin_amdgcn_mfma_f32_16x16x32_bf16(af[mt], bfr[nt], acc[mt][nt], 0, 0, 0);
    }
    __syncthreads();
  }
  int lr = lane & 15;
#pragma unroll
  for (int mt = 0; mt < 4; mt++){
    int rbase = mh * 64 + mt * 16 + ((lane >> 4) << 2);
#pragma unroll
    for (int j = 0; j < 4; j++){
      int r = rbase + j;
      int ai = r >> 5;
      if (ai >= na) continue;
      size_t grow = (size_t)(arow[ai] * NB + (r & 31));
#pragma unroll
      for (int nt = 0; nt < 4; nt++){
        int col = n0 + nh * 64 + nt * 16 + lr;
        float v = acc[mt][nt][j] + b_in[spec * HID + col];
        v = v > 0.f ? v : 0.f;
        xproj[grow * HID + col] = (ushort)f2bf1(v);
      }
    }
  }
}

// ---------------- stage 2: gates (i,g,o only) + fused LSTM cell -> h1, c1 ----------------
// grid (16 col-tiles of 32, 128 m-tiles of 128), 256 threads.
__global__ __launch_bounds__(256) void k_lstm(
    const ushort* __restrict__ xproj, const float* __restrict__ w_ih,
    const float* __restrict__ b_ih, const float* __restrict__ b_hh,
    float* __restrict__ hout, float* __restrict__ cout_)
{
  int n0 = blockIdx.x * 32;
  int m0 = blockIdx.y * 128;
  int tid = threadIdx.x, lane = tid & 63, wid = tid >> 6;   // wid = m-half (rows of 32)

  __shared__ uint4 ldsA[128 * 8];
  __shared__ uint4 ldsB[96 * 8];

  f32x4 acc[2][6];
#pragma unroll
  for (int i = 0; i < 2; i++)
#pragma unroll
    for (int j = 0; j < 6; j++) acc[i][j] = (f32x4){0.f, 0.f, 0.f, 0.f};

  for (int ch = 0; ch < 8; ++ch){
    int k0 = ch * 64;
#pragma unroll
    for (int i = 0; i < 4; i++){            // A: x_proj rows (already bf16)
      int u = tid + i * 256;
      int r = u >> 3, uu = u & 7;
      const uint4* src = reinterpret_cast<const uint4*>(xproj + (size_t)(m0 + r) * HID + k0 + uu * 8);
      ldsA[r * 8 + (uu ^ (r & 7))] = *src;
    }
#pragma unroll
    for (int i = 0; i < 3; i++){            // B: w_ih rows for gates i,g,o
      int u = tid + i * 256;
      int r = u >> 3, uu = u & 7;
      int gate = r >> 5;
      int gbase = (gate == 0) ? 0 : ((gate == 1) ? 1024 : 1536);
      const float* src = w_ih + (size_t)(gbase + n0 + (r & 31)) * HID + k0 + uu * 8;
      ldsB[r * 8 + (uu ^ (r & 7))] = load8_pack(src);
    }
    __syncthreads();
#pragma unroll
    for (int kk = 0; kk < 2; ++kk){
      int lr = lane & 15, lk = (lane >> 4) + kk * 4;
      bf16x8 af[2], bfr[6];
#pragma unroll
      for (int mt = 0; mt < 2; mt++){
        int r = wid * 32 + mt * 16 + lr;
        af[mt] = __builtin_bit_cast(bf16x8, ldsA[r * 8 + (lk ^ (r & 7))]);
      }
#pragma unroll
      for (int gn = 0; gn < 6; gn++){
        int r = gn * 16 + lr;
        bfr[gn] = __builtin_bit_cast(bf16x8, ldsB[r * 8 + (lk ^ (r & 7))]);
      }
#pragma unroll
      for (int mt = 0; mt < 2; mt++)
#pragma unroll
        for (int gn = 0; gn < 6; gn++)
          acc[mt][gn] = __builtin_amdgcn_mfma_f32_16x16x32_bf16(af[mt], bfr[gn], acc[mt][gn], 0, 0, 0);
    }
    __syncthreads();
  }
  int lr = lane & 15;
#pragma unroll
  for (int mt = 0; mt < 2; mt++){
    int rbase = m0 + wid * 32 + mt * 16 + ((lane >> 4) << 2);
#pragma unroll
    for (int ntg = 0; ntg < 2; ntg++){
      int c = n0 + ntg * 16 + lr;
      float bi0 = b_ih[c]        + b_hh[c];
      float bi1 = b_ih[1024 + c] + b_hh[1024 + c];
      float bi2 = b_ih[1536 + c] + b_hh[1536 + c];
#pragma unroll
      for (int j = 0; j < 4; j++){
        float gi = acc[mt][0 + ntg][j] + bi0;
        float gg = acc[mt][2 + ntg][j] + bi1;
        float go = acc[mt][4 + ntg][j] + bi2;
        float iv = sigm(gi);
        float gv = tanhf(gg);
        float ov = sigm(go);
        float c1 = iv * gv;
        float h1 = ov * tanhf(c1);
        size_t idx = (size_t)(rbase + j) * HID + c;
        hout[idx] = h1;
        cout_[idx] = c1;
      }
    }
  }
}

// ---------------- stage 4: logits = h1 @ w_out[s]^T + b_out[s] ----------------
// grid (8 ntiles of 128, NSLOTS), 256 threads. BM=128 (4 a), K=512.
__global__ __launch_bounds__(256) void k_logits(
    const float* __restrict__ h1, const float* __restrict__ w_out,
    const float* __restrict__ b_out,
    const int* __restrict__ order, const int* __restrict__ slot_s,
    const int* __restrict__ slot_st, const int* __restrict__ slot_na,
    float* __restrict__ logits)
{
  int slot = blockIdx.y;
  int na = slot_na[slot];
  if (na == 0) return;
  int spec = slot_s[slot];
  int start = slot_st[slot];
  int n0 = blockIdx.x * 128;
  int tid = threadIdx.x, lane = tid & 63, wid = tid >> 6;
  int mh = wid >> 1, nh = wid & 1;

  __shared__ uint4 ldsA[128 * 8];
  __shared__ uint4 ldsB[128 * 8];

  int arow[4];
#pragma unroll
  for (int i = 0; i < 4; i++) arow[i] = (i < na) ? order[start + i] : 0;

  f32x4 acc[4][4];
#pragma unroll
  for (int i = 0; i < 4; i++)
#pragma unroll
    for (int j = 0; j < 4; j++) acc[i][j] = (f32x4){0.f, 0.f, 0.f, 0.f};

  for (int ch = 0; ch < 8; ++ch){
    int k0 = ch * 64;
#pragma unroll
    for (int i = 0; i < 4; i++){            // A: h1 rows fp32 -> bf16 (masked)
      int u = tid + i * 256;
      int r = u >> 3, uu = u & 7;
      int ai = r >> 5;
      uint4 v = {0u, 0u, 0u, 0u};
      if (ai < na){
        const float* src = h1 + ((size_t)(arow[ai] * NB + (r & 31))) * HID + k0 + uu * 8;
        v = load8_pack(src);
      }
      ldsA[r * 8 + (uu ^ (r & 7))] = v;
    }
#pragma unroll
    for (int i = 0; i < 4; i++){            // B: w_out[s] rows fp32 -> bf16
      int u = tid + i * 256;
      int r = u >> 3, uu = u & 7;
      const float* src = w_out + ((size_t)(spec * ODIM + n0 + r)) * HID + k0 + uu * 8;
      ldsB[r * 8 + (uu ^ (r & 7))] = load8_pack(src);
    }
    __syncthreads();
#pragma unroll
    for (int kk = 0; kk < 2; ++kk){
      int lr = lane & 15, lk = (lane >> 4) + kk * 4;
      bf16x8 af[4], bfr[4];
#pragma unroll
      for (int mt = 0; mt < 4; mt++){
        int r = mh * 64 + mt * 16 + lr;
        af[mt] = __builtin_bit_cast(bf16x8, ldsA[r * 8 + (lk ^ (r & 7))]);
      }
#pragma unroll
      for (int nt = 0; nt < 4; nt++){
        int r = nh * 64 + nt * 16 + lr;
        bfr[nt] = __builtin_bit_cast(bf16x8, ldsB[r * 8 + (lk ^ (r & 7))]);
      }
#pragma unroll
      for (int mt = 0; mt < 4; mt++)
#pragma unroll
        for (int nt = 0; nt < 4; nt++)
          acc[mt][nt] = __builtin_amdgcn_mfma_f32_16x16x32_bf16(af[mt], bfr[nt], acc[mt][nt], 0, 0, 0);
    }
    __syncthreads();
  }
  int lr = lane & 15;
#pragma unroll
  for (int mt = 0; mt < 4; mt++){
    int rbase = mh * 64 + mt * 16 + ((lane >> 4) << 2);
#pragma unroll
    for (int j = 0; j < 4; j++){
      int r = rbase + j;
      int ai = r >> 5;
      if (ai >= na) continue;
      size_t grow = (size_t)(arow[ai] * NB + (r & 31));
#pragma unroll
      for (int nt = 0; nt < 4; nt++){
        int col = n0 + nh * 64 + nt * 16 + lr;
        float v = acc[mt][nt][j] + b_out[spec * ODIM + col];
        logits[grow * ODIM + col] = v;
      }
    }
  }
}

extern "C" void kernel_launch(void* const* d_in, const int* in_sizes, int n_in,
                              void* d_out, int out_size, void* d_ws, size_t ws_size,
                              hipStream_t stream){
  const float* x     = (const float*)d_in[0];
  const int*   sp    = (const int*)  d_in[1];
  const float* w_in  = (const float*)d_in[2];
  const float* b_in  = (const float*)d_in[3];
  const float* w_ih  = (const float*)d_in[4];
  // d_in[5] = w_hh: unused (h0 == 0)
  const float* b_ih  = (const float*)d_in[6];
  const float* b_hh  = (const float*)d_in[7];
  const float* w_out = (const float*)d_in[8];
  const float* b_out = (const float*)d_in[9];

  float* out    = (float*)d_out;
  float* logits = out;                                   // 16384*1024
  float* hout   = out + (size_t)NROWS * ODIM;            // 16384*512
  float* cout_  = hout + (size_t)NROWS * HID;            // 16384*512
  // x_proj bf16 scratch lives in the (not-yet-written) logits region:
  ushort* xproj = (ushort*)d_out;                        // 16384*512 bf16 = 16.8 MB < 64 MB

  int* order   = (int*)d_ws;           // 512
  int* slot_s  = order + NA;           // 144
  int* slot_st = slot_s + NSLOTS;      // 144
  int* slot_na = slot_st + NSLOTS;     // 144

  k_prep<<<1, 512, 0, stream>>>(sp, order, slot_s, slot_st, slot_na);
  k_xproj<<<dim3(4, NSLOTS), 256, 0, stream>>>(x, w_in, b_in, order, slot_s, slot_st, slot_na, xproj);
  k_lstm<<<dim3(16, 128), 256, 0, stream>>>(xproj, w_ih, b_ih, b_hh, hout, cout_);
  k_logits<<<dim3(8, NSLOTS), 256, 0, stream>>>(hout, w_out, b_out, order, slot_s, slot_st, slot_na, logits);
}

// Round 2
// 325.859 us; speedup vs baseline: 1.0206x; 1.0206x over previous
//
#include <hip/hip_runtime.h>
#include <stdint.h>

#define NSPEC 16
#define IN_DIM 256
#define HID 512
#define ODIM 1024
#define NA 512
#define NB 32
#define NROWS (NA*NB)
#define NSLOTS 144

typedef __bf16 bf16x8 __attribute__((ext_vector_type(8)));
typedef float f32x4 __attribute__((ext_vector_type(4)));

// async global->LDS, 16B per lane. LDS dest must be wave-uniform; global src per-lane.
#define GLOAD16(g, l) __builtin_amdgcn_global_load_lds( \
    (const __attribute__((address_space(1))) void*)(g), \
    (__attribute__((address_space(3))) void*)(l), 16, 0, 0)

__device__ __forceinline__ uint32_t f2bf1(float f){
  uint32_t u = __builtin_bit_cast(uint32_t, f);
  u += 0x7FFFu + ((u >> 16) & 1u);   // RNE
  return u >> 16;
}
__device__ __forceinline__ uint32_t pack2(float a, float b){
  return f2bf1(a) | (f2bf1(b) << 16);
}
__device__ __forceinline__ uint4 load8_pack(const float* __restrict__ src){
  float4 f0 = *reinterpret_cast<const float4*>(src);
  float4 f1 = *reinterpret_cast<const float4*>(src + 4);
  uint4 v;
  v.x = pack2(f0.x, f0.y); v.y = pack2(f0.z, f0.w);
  v.z = pack2(f1.x, f1.y); v.w = pack2(f1.z, f1.w);
  return v;
}
__device__ __forceinline__ float sigm(float x){ return 1.0f / (1.0f + __expf(-x)); }

// ---------------- prep: group a-indices by species into slots of <=4 ----------------
__global__ void k_prep(const int* __restrict__ sp, int* __restrict__ order,
                       int* __restrict__ slot_s, int* __restrict__ slot_st,
                       int* __restrict__ slot_na){
  __shared__ int cnt[NSPEC], off[NSPEC], cur[NSPEC];
  int t = threadIdx.x;
  if (t < NSPEC) cnt[t] = 0;
  __syncthreads();
  int s = sp[t];
  atomicAdd(&cnt[s], 1);
  __syncthreads();
  if (t == 0){
    int o = 0;
    for (int i = 0; i < NSPEC; i++){ off[i] = o; cur[i] = o; o += cnt[i]; }
  }
  __syncthreads();
  int pos = atomicAdd(&cur[s], 1);
  order[pos] = t;
  __syncthreads();
  if (t == 0){
    int k = 0;
    for (int i = 0; i < NSPEC; i++){
      int c = cnt[i], st = off[i];
      for (int j = 0; j < c; j += 4){
        slot_s[k] = i; slot_st[k] = st + j;
        slot_na[k] = (c - j < 4) ? (c - j) : 4; k++;
      }
    }
    for (; k < NSLOTS; k++){ slot_s[k] = 0; slot_st[k] = 0; slot_na[k] = 0; }
  }
}

// ---------------- conv: fp32 weights -> bf16, pre-swizzled (XOR 16B-unit by row&7) ----------------
// wi: [16][512][256], wg: [1536][512] (gates i,g,o from w_ih rows 0/1024/1536), wo: [16][1024][512]
__global__ __launch_bounds__(256) void k_conv(
    const float* __restrict__ w_in, const float* __restrict__ w_ih,
    const float* __restrict__ w_out,
    ushort* __restrict__ wi, ushort* __restrict__ wg, ushort* __restrict__ wo,
    int do_wo)
{
  const int U1 = NSPEC*HID*IN_DIM/8;   // 262144
  const int U2 = 3*HID*HID/8;          // 98304
  const int U3 = NSPEC*ODIM*HID/8;     // 1048576
  int total = U1 + U2 + (do_wo ? U3 : 0);
  for (int u = blockIdx.x*256 + threadIdx.x; u < total; u += gridDim.x*256){
    const float* src; ushort* drow; int row, col;
    if (u < U1){
      int e = u*8; row = e >> 8; col = e & 255;
      src = w_in + (size_t)row*IN_DIM + col;
      drow = wi + (size_t)row*IN_DIM;
    } else if (u < U1+U2){
      int e = (u-U1)*8; row = e >> 9; col = e & 511;
      int g = row >> 9;
      int srow = (g==0 ? 0 : (g==1 ? 1024 : 1536)) + (row & 511);
      src = w_ih + (size_t)srow*HID + col;
      drow = wg + (size_t)row*HID;
    } else {
      int e = (u-U1-U2)*8; row = e >> 9; col = e & 511;
      src = w_out + (size_t)row*HID + col;
      drow = wo + (size_t)row*HID;
    }
    uint4 v = load8_pack(src);
    int colp = (col & ~63) | ((((col >> 3) & 7) ^ (row & 7)) << 3);
    *reinterpret_cast<uint4*>(drow + colp) = v;
  }
}

// ---------------- stage 1: x_proj = relu(x @ w_in[s]^T + b_in[s]) -> bf16 (swizzled) ----------------
__global__ __launch_bounds__(256) void k_xproj(
    const float* __restrict__ x, const ushort* __restrict__ wi,
    const float* __restrict__ b_in,
    const int* __restrict__ order, const int* __restrict__ slot_s,
    const int* __restrict__ slot_st, const int* __restrict__ slot_na,
    ushort* __restrict__ xproj)
{
  int slot = blockIdx.y;
  int na = slot_na[slot];
  if (na == 0) return;
  int spec = slot_s[slot];
  int start = slot_st[slot];
  int n0 = blockIdx.x * 128;
  int tid = threadIdx.x, lane = tid & 63, wid = tid >> 6;
  int mh = wid >> 1, nh = wid & 1;
  int lrow = lane >> 3, lseg = lane & 7;

  __shared__ uint4 ldsA[128 * 8];
  __shared__ uint4 ldsB[128 * 8];

  int arow[4];
#pragma unroll
  for (int i = 0; i < 4; i++) arow[i] = (i < na) ? order[start + i] : 0;

  f32x4 acc[4][4];
#pragma unroll
  for (int i = 0; i < 4; i++)
#pragma unroll
    for (int j = 0; j < 4; j++) acc[i][j] = (f32x4){0.f, 0.f, 0.f, 0.f};

  for (int ch = 0; ch < 4; ++ch){
    int k0 = ch * 64;
#pragma unroll
    for (int i = 0; i < 4; i++){            // A: x rows fp32->bf16 (masked), reg-staged
      int u = tid + i * 256;
      int r = u >> 3, uu = u & 7;
      int ai = r >> 5;
      uint4 v = {0u, 0u, 0u, 0u};
      if (ai < na){
        const float* src = x + ((size_t)(arow[ai] * NB + (r & 31))) * IN_DIM + k0 + uu * 8;
        v = load8_pack(src);
      }
      ldsA[r * 8 + (uu ^ (r & 7))] = v;
    }
#pragma unroll
    for (int i = 0; i < 4; i++){            // B: wi pre-swizzled, async to LDS
      int rr = wid * 32 + i * 8 + lrow;
      const ushort* bsrc = wi + (size_t)(spec * HID + n0 + rr) * IN_DIM + k0 + lseg * 8;
      GLOAD16(bsrc, &ldsB[(wid * 32 + i * 8) * 8]);
    }
    __syncthreads();
#pragma unroll
    for (int kk = 0; kk < 2; ++kk){
      int lr = lane & 15, lk = (lane >> 4) + kk * 4;
      bf16x8 af[4], bfr[4];
#pragma unroll
      for (int mt = 0; mt < 4; mt++){
        int r = mh * 64 + mt * 16 + lr;
        af[mt] = __builtin_bit_cast(bf16x8, ldsA[r * 8 + (lk ^ (r & 7))]);
      }
#pragma unroll
      for (int nt = 0; nt < 4; nt++){
        int r = nh * 64 + nt * 16 + lr;
        bfr[nt] = __builtin_bit_cast(bf16x8, ldsB[r * 8 + (lk ^ (r & 7))]);
      }
#pragma unroll
      for (int mt = 0; mt < 4; mt++)
#pragma unroll
        for (int nt = 0; nt < 4; nt++)
          acc[mt][nt] = __builtin_amdgcn_mfma_f32_16x16x32_bf16(af[mt], bfr[nt], acc[mt][nt], 0, 0, 0);
    }
    __syncthreads();
  }
  int lr = lane & 15;
#pragma unroll
  for (int mt = 0; mt < 4; mt++){
    int rbase = mh * 64 + mt * 16 + ((lane >> 4) << 2);
#pragma unroll
    for (int j = 0; j < 4; j++){
      int r = rbase + j;
      int ai = r >> 5;
      if (ai >= na) continue;
      int grow = arow[ai] * NB + (r & 31);
#pragma unroll
      for (int nt = 0; nt < 4; nt++){
        int col = n0 + nh * 64 + nt * 16 + lr;
        float v = acc[mt][nt][j] + b_in[spec * HID + col];
        v = v > 0.f ? v : 0.f;
        // swizzled store: permute 16B-unit within 64-col segment by row&7
        int colp = (col & ~63) | ((((col >> 3) & 7) ^ (grow & 7)) << 3) | (col & 7);
        xproj[(size_t)grow * HID + colp] = (ushort)f2bf1(v);
      }
    }
  }
}

// ---------------- stage 2: gates (i,g,o) + fused LSTM cell -> h1, c1 ----------------
// BM=128, BN=64/gate (192 cols), BK=64, 8 chunks. grid (8, 128).
__global__ __launch_bounds__(256) void k_lstm(
    const ushort* __restrict__ xproj, const ushort* __restrict__ wg,
    const float* __restrict__ b_ih, const float* __restrict__ b_hh,
    float* __restrict__ hout, float* __restrict__ cout_)
{
  int n0 = blockIdx.x * 64;       // gate-local col base
  int m0 = blockIdx.y * 128;
  int tid = threadIdx.x, lane = tid & 63, wid = tid >> 6;
  int mh = wid >> 1, nh = wid & 1;   // wave tile: 64 rows x (32 cols x 3 gates)
  int lrow = lane >> 3, lseg = lane & 7;

  __shared__ uint4 ldsA[128 * 8];   // [128][64] bf16 swz
  __shared__ uint4 ldsB[192 * 8];   // [3*64][64] bf16 swz

  f32x4 acc[4][6];
#pragma unroll
  for (int i = 0; i < 4; i++)
#pragma unroll
    for (int j = 0; j < 6; j++) acc[i][j] = (f32x4){0.f, 0.f, 0.f, 0.f};

  for (int ch = 0; ch < 8; ++ch){
    int k0 = ch * 64;
    const ushort* asrc = xproj + (size_t)(m0 + wid * 32 + lrow) * HID + k0 + lseg * 8;
#pragma unroll
    for (int i = 0; i < 4; i++){            // A: xproj (pre-swizzled bf16) async
      GLOAD16(asrc + (size_t)i * 8 * HID, &ldsA[(wid * 32 + i * 8) * 8]);
    }
#pragma unroll
    for (int i = 0; i < 6; i++){            // B: wg (pre-swizzled bf16) async
      int rr = wid * 48 + i * 8 + lrow;
      int g = rr >> 6;
      const ushort* bsrc = wg + (size_t)(g * HID + n0 + (rr & 63)) * HID + k0 + lseg * 8;
      GLOAD16(bsrc, &ldsB[(wid * 48 + i * 8) * 8]);
    }
    __syncthreads();
#pragma unroll
    for (int kk = 0; kk < 2; ++kk){
      int lr = lane & 15, lk = (lane >> 4) + kk * 4;
      bf16x8 af[4], bfr[6];
#pragma unroll
      for (int mt = 0; mt < 4; mt++){
        int r = mh * 64 + mt * 16 + lr;
        af[mt] = __builtin_bit_cast(bf16x8, ldsA[r * 8 + (lk ^ (r & 7))]);
      }
#pragma unroll
      for (int g = 0; g < 3; g++)
#pragma unroll
        for (int t = 0; t < 2; t++){
          int rr = g * 64 + nh * 32 + t * 16 + lr;
          bfr[g * 2 + t] = __builtin_bit_cast(bf16x8, ldsB[rr * 8 + (lk ^ (rr & 7))]);
        }
#pragma unroll
      for (int mt = 0; mt < 4; mt++)
#pragma unroll
        for (int gn = 0; gn < 6; gn++)
          acc[mt][gn] = __builtin_amdgcn_mfma_f32_16x16x32_bf16(af[mt], bfr[gn], acc[mt][gn], 0, 0, 0);
    }
    __syncthreads();
  }
  int lr = lane & 15;
#pragma unroll
  for (int t = 0; t < 2; t++){
    int c = n0 + nh * 32 + t * 16 + lr;      // gate-local column 0..511
    float bi0 = b_ih[c]        + b_hh[c];
    float bi1 = b_ih[1024 + c] + b_hh[1024 + c];
    float bi2 = b_ih[1536 + c] + b_hh[1536 + c];
#pragma unroll
    for (int mt = 0; mt < 4; mt++){
      int rbase = m0 + mh * 64 + mt * 16 + ((lane >> 4) << 2);
#pragma unroll
      for (int j = 0; j < 4; j++){
        float gi = acc[mt][0 + t][j] + bi0;
        float gg = acc[mt][2 + t][j] + bi1;
        float go = acc[mt][4 + t][j] + bi2;
        float iv = sigm(gi);
        float gv = tanhf(gg);
        float ov = sigm(go);
        float c1 = iv * gv;
        float h1 = ov * tanhf(c1);
        size_t idx = (size_t)(rbase + j) * HID + c;
        hout[idx] = h1;
        cout_[idx] = c1;
      }
    }
  }
}

// ---------------- stage 4: logits = h1 @ w_out[s]^T + b_out[s] ----------------
template<bool PRE>
__global__ __launch_bounds__(256) void k_logits(
    const float* __restrict__ h1, const ushort* __restrict__ wo,
    const float* __restrict__ w_out, const float* __restrict__ b_out,
    const int* __restrict__ order, const int* __restrict__ slot_s,
    const int* __restrict__ slot_st, const int* __restrict__ slot_na,
    float* __restrict__ logits)
{
  int slot = blockIdx.y;
  int na = slot_na[slot];
  if (na == 0) return;
  int spec = slot_s[slot];
  int start = slot_st[slot];
  int n0 = blockIdx.x * 128;
  int tid = threadIdx.x, lane = tid & 63, wid = tid >> 6;
  int mh = wid >> 1, nh = wid & 1;
  int lrow = lane >> 3, lseg = lane & 7;

  __shared__ uint4 ldsA[128 * 8];
  __shared__ uint4 ldsB[128 * 8];

  int arow[4];
#pragma unroll
  for (int i = 0; i < 4; i++) arow[i] = (i < na) ? order[start + i] : 0;

  f32x4 acc[4][4];
#pragma unroll
  for (int i = 0; i < 4; i++)
#pragma unroll
    for (int j = 0; j < 4; j++) acc[i][j] = (f32x4){0.f, 0.f, 0.f, 0.f};

  for (int ch = 0; ch < 8; ++ch){
    int k0 = ch * 64;
#pragma unroll
    for (int i = 0; i < 4; i++){            // A: h1 fp32 -> bf16 (masked), reg-staged
      int u = tid + i * 256;
      int r = u >> 3, uu = u & 7;
      int ai = r >> 5;
      uint4 v = {0u, 0u, 0u, 0u};
      if (ai < na){
        const float* src = h1 + ((size_t)(arow[ai] * NB + (r & 31))) * HID + k0 + uu * 8;
        v = load8_pack(src);
      }
      ldsA[r * 8 + (uu ^ (r & 7))] = v;
    }
    if (PRE){
#pragma unroll
      for (int i = 0; i < 4; i++){          // B: wo pre-swizzled, async
        int rr = wid * 32 + i * 8 + lrow;
        const ushort* bsrc = wo + (size_t)(spec * ODIM + n0 + rr) * HID + k0 + lseg * 8;
        GLOAD16(bsrc, &ldsB[(wid * 32 + i * 8) * 8]);
      }
    } else {
#pragma unroll
      for (int i = 0; i < 4; i++){          // B: w_out fp32 pack fallback
        int u = tid + i * 256;
        int r = u >> 3, uu = u & 7;
        const float* src = w_out + ((size_t)(spec * ODIM + n0 + r)) * HID + k0 + uu * 8;
        ldsB[r * 8 + (uu ^ (r & 7))] = load8_pack(src);
      }
    }
    __syncthreads();
#pragma unroll
    for (int kk = 0; kk < 2; ++kk){
      int lr = lane & 15, lk = (lane >> 4) + kk * 4;
      bf16x8 af[4], bfr[4];
#pragma unroll
      for (int mt = 0; mt < 4; mt++){
        int r = mh * 64 + mt * 16 + lr;
        af[mt] = __builtin_bit_cast(bf16x8, ldsA[r * 8 + (lk ^ (r & 7))]);
      }
#pragma unroll
      for (int nt = 0; nt < 4; nt++){
        int r = nh * 64 + nt * 16 + lr;
        bfr[nt] = __builtin_bit_cast(bf16x8, ldsB[r * 8 + (lk ^ (r & 7))]);
      }
#pragma unroll
      for (int mt = 0; mt < 4; mt++)
#pragma unroll
        for (int nt = 0; nt < 4; nt++)
          acc[mt][nt] = __builtin_amdgcn_mfma_f32_16x16x32_bf16(af[mt], bfr[nt], acc[mt][nt], 0, 0, 0);
    }
    __syncthreads();
  }
  int lr = lane & 15;
#pragma unroll
  for (int mt = 0; mt < 4; mt++){
    int rbase = mh * 64 + mt * 16 + ((lane >> 4) << 2);
#pragma unroll
    for (int j = 0; j < 4; j++){
      int r = rbase + j;
      int ai = r >> 5;
      if (ai >= na) continue;
      size_t grow = (size_t)(arow[ai] * NB + (r & 31));
#pragma unroll
      for (int nt = 0; nt < 4; nt++){
        int col = n0 + nh * 64 + nt * 16 + lr;
        float v = acc[mt][nt][j] + b_out[spec * ODIM + col];
        logits[grow * ODIM + col] = v;
      }
    }
  }
}

extern "C" void kernel_launch(void* const* d_in, const int* in_sizes, int n_in,
                              void* d_out, int out_size, void* d_ws, size_t ws_size,
                              hipStream_t stream){
  const float* x     = (const float*)d_in[0];
  const int*   sp    = (const int*)  d_in[1];
  const float* w_in  = (const float*)d_in[2];
  const float* b_in  = (const float*)d_in[3];
  const float* w_ih  = (const float*)d_in[4];
  // d_in[5] = w_hh: unused (h0 == 0)
  const float* b_ih  = (const float*)d_in[6];
  const float* b_hh  = (const float*)d_in[7];
  const float* w_out = (const float*)d_in[8];
  const float* b_out = (const float*)d_in[9];

  float* out    = (float*)d_out;
  float* logits = out;                                   // 16384*1024 f32 (64MB)
  float* hout   = out + (size_t)NROWS * ODIM;            // 16384*512 f32
  float* cout_  = hout + (size_t)NROWS * HID;            // 16384*512 f32
  // scratch living inside the not-yet-written logits region:
  ushort* xproj = (ushort*)d_out;                        // 16MB, dead after k_lstm
  ushort* wi_bf = xproj + (size_t)NROWS * HID;           // 4MB, dead after k_xproj
  ushort* wg_bf = wi_bf + (size_t)NSPEC * HID * IN_DIM;  // 1.5MB, dead after k_lstm

  int* order   = (int*)d_ws;           // 512
  int* slot_s  = order + NA;           // 144
  int* slot_st = slot_s + NSLOTS;      // 144
  int* slot_na = slot_st + NSLOTS;     // 144  (total 3776B < 4096)
  ushort* wo_bf = (ushort*)((char*)d_ws + 4096);         // 16MB if available

  size_t need = 4096 + (size_t)NSPEC * ODIM * HID * 2;
  bool pre = ws_size >= need;

  k_prep<<<1, NA, 0, stream>>>(sp, order, slot_s, slot_st, slot_na);
  k_conv<<<1024, 256, 0, stream>>>(w_in, w_ih, w_out, wi_bf, wg_bf, wo_bf, pre ? 1 : 0);
  k_xproj<<<dim3(4, NSLOTS), 256, 0, stream>>>(x, wi_bf, b_in, order, slot_s, slot_st, slot_na, xproj);
  k_lstm<<<dim3(8, 128), 256, 0, stream>>>(xproj, wg_bf, b_ih, b_hh, hout, cout_);
  if (pre)
    k_logits<true><<<dim3(8, NSLOTS), 256, 0, stream>>>(hout, wo_bf, w_out, b_out, order, slot_s, slot_st, slot_na, logits);
  else
    k_logits<false><<<dim3(8, NSLOTS), 256, 0, stream>>>(hout, wo_bf, w_out, b_out, order, slot_s, slot_st, slot_na, logits);
}